// Round 1
// baseline (40133.221 us; speedup 1.0000x reference)
//
#include <hip/hip_runtime.h>
#include <math.h>

#define HID 256
#define BSZ 64
#define TLEN 256
#define INW 64
#define OUTW 32
#define NOISE_STD 0.05f
#define TAU 0.2f

// ---------------------------------------------------------------------------
// init: x = x0, r = tanh(x0), rT = transpose(r)
// ---------------------------------------------------------------------------
__global__ __launch_bounds__(256) void init_kernel(const float* __restrict__ x0,
                                                   float* __restrict__ x,
                                                   float* __restrict__ r,
                                                   float* __restrict__ rT) {
    int idx = blockIdx.x * 256 + threadIdx.x;   // 0..16383
    float v = x0[idx];
    x[idx] = v;
    float rv = tanhf(v);
    r[idx] = rv;
    int b = idx >> 8, j = idx & 255;
    rT[j * BSZ + b] = rv;
}

// ---------------------------------------------------------------------------
// one recurrent step. block = output column j (256 blocks), thread = k lane.
// rec[b,j] = input_I + W1 + sum_k r[b,k] * ( sum_i r[b,i] * W[j,i,k] )
// Lane tid owns k=tid: S[b] += W[j,i,tid] * rT_in[i*64+b]  (scalar operand)
// ---------------------------------------------------------------------------
__global__ __launch_bounds__(256) void step_kernel(
    const float* __restrict__ W,       // [HID][HID][HID]
    const float* __restrict__ w_hh,    // [HID][HID]
    const float* __restrict__ u,       // [B][T][IN]
    const float* __restrict__ w_in_w,  // [HID][IN]
    const float* __restrict__ w_in_b,  // [HID]
    const float* __restrict__ noise_t, // [B][HID] slice for this t
    const float* __restrict__ r_in,    // [B][HID]
    const float* __restrict__ rT_in,   // [HID][B]
    float* __restrict__ x,             // [B][HID] (in-place; block j owns col j)
    float* __restrict__ r_out,         // [B][HID]
    float* __restrict__ rT_out,        // [HID][B]
    float* __restrict__ traj,          // [B][T][HID] (d_out region)
    int t) {
    __shared__ float red[BSZ][HID + 1];   // padded: conflict-free both phases
    __shared__ float red2[BSZ][4];

    const int tid = threadIdx.x;          // k lane 0..255
    const int j = blockIdx.x;
    const float* __restrict__ Wj = W + (size_t)j * HID * HID;

    float S[BSZ];
#pragma unroll
    for (int b = 0; b < BSZ; ++b) S[b] = 0.f;

    // main loop over i, 4-deep W prefetch per iteration
    for (int i0 = 0; i0 < HID; i0 += 4) {
        float w0 = Wj[(i0 + 0) * HID + tid];   // coalesced 1KB row reads
        float w1 = Wj[(i0 + 1) * HID + tid];
        float w2 = Wj[(i0 + 2) * HID + tid];
        float w3 = Wj[(i0 + 3) * HID + tid];
        const float* __restrict__ r0p = rT_in + (size_t)(i0 + 0) * BSZ;  // uniform -> s_load
        const float* __restrict__ r1p = rT_in + (size_t)(i0 + 1) * BSZ;
        const float* __restrict__ r2p = rT_in + (size_t)(i0 + 2) * BSZ;
        const float* __restrict__ r3p = rT_in + (size_t)(i0 + 3) * BSZ;
#pragma unroll
        for (int b = 0; b < BSZ; ++b) {
            S[b] = fmaf(w0, r0p[b], S[b]);
            S[b] = fmaf(w1, r1p[b], S[b]);
            S[b] = fmaf(w2, r2p[b], S[b]);
            S[b] = fmaf(w3, r3p[b], S[b]);
        }
    }

    // contrib[b] = r[b][tid] * S[b];  r[b][tid] == rT_in[tid*64+b] (contiguous per lane)
    {
        const float* __restrict__ rk = rT_in + (size_t)tid * BSZ;
#pragma unroll
        for (int b = 0; b < BSZ; ++b) red[b][tid] = rk[b] * S[b];
    }
    __syncthreads();

    // reduce 256 k-partials per b: 256 threads = 64 b x 4 quarters
    {
        int rb = tid & 63, q = tid >> 6;
        float psum = 0.f;
#pragma unroll 8
        for (int m = q * 64; m < q * 64 + 64; ++m) psum += red[rb][m];
        red2[rb][q] = psum;
    }
    __syncthreads();

    if (tid < BSZ) {
        const int b = tid;
        float rec = red2[b][0] + red2[b][1] + red2[b][2] + red2[b][3];

        // hidden_W1[b,j] = sum_i r[b,i] * w_hh[j,i]   (w_hh row uniform -> s_load)
        float w1sum = 0.f;
        const float* __restrict__ rrow = r_in + (size_t)b * HID;
        const float* __restrict__ hrow = w_hh + (size_t)j * HID;
#pragma unroll 8
        for (int i = 0; i < HID; ++i) w1sum = fmaf(rrow[i], hrow[i], w1sum);

        // input_I[b,j] = w_in_b[j] + sum_in u[b,t,in] * w_in_w[j,in]
        float isum = w_in_b[j];
        const float* __restrict__ urow = u + ((size_t)b * TLEN + t) * INW;
        const float* __restrict__ wrow = w_in_w + (size_t)j * INW;
#pragma unroll 8
        for (int in_ = 0; in_ < INW; ++in_) isum = fmaf(urow[in_], wrow[in_], isum);

        rec += w1sum + isum;

        const int xi = b * HID + j;
        float xo = x[xi];
        float xn = xo + NOISE_STD * noise_t[xi] + TAU * (rec - xo);
        x[xi] = xn;
        traj[((size_t)b * TLEN + t) * HID + j] = xn;
        float rn = tanhf(xn);
        r_out[xi] = rn;
        rT_out[j * BSZ + b] = rn;
    }
}

// ---------------------------------------------------------------------------
// x_final copy
// ---------------------------------------------------------------------------
__global__ __launch_bounds__(256) void xfinal_kernel(const float* __restrict__ x,
                                                     float* __restrict__ xf) {
    int idx = blockIdx.x * 256 + threadIdx.x;
    xf[idx] = x[idx];
}

// ---------------------------------------------------------------------------
// output[b,t,o] = w_out_b[o] + sum_h tanh(traj[b,t,h]) * w_out_w[o,h]
// block = 8 consecutive (b,t) rows; tanh staged once in LDS (padded rows)
// ---------------------------------------------------------------------------
__global__ __launch_bounds__(256) void output_kernel(
    const float* __restrict__ traj,     // [B][T][HID]
    const float* __restrict__ w_out_w,  // [OUT][HID]
    const float* __restrict__ w_out_b,  // [OUT]
    float* __restrict__ out) {          // [B][T][OUT]
    __shared__ float th[8][HID + 1];
    const int bt0 = blockIdx.x * 8;
    const int tid = threadIdx.x;
#pragma unroll
    for (int m = 0; m < 8; ++m) {
        int idx = m * 256 + tid;
        th[idx >> 8][idx & 255] = tanhf(traj[(size_t)bt0 * HID + idx]);
    }
    __syncthreads();
    const int row = tid >> 5, o = tid & 31;
    const float* __restrict__ wrow = w_out_w + (size_t)o * HID;
    float s = w_out_b[o];
#pragma unroll 8
    for (int h = 0; h < HID; ++h) s = fmaf(th[row][h], wrow[h], s);
    out[(size_t)(bt0 + row) * OUTW + o] = s;
}

// ---------------------------------------------------------------------------
extern "C" void kernel_launch(void* const* d_in, const int* in_sizes, int n_in,
                              void* d_out, int out_size, void* d_ws, size_t ws_size,
                              hipStream_t stream) {
    const float* u       = (const float*)d_in[0];  // [B][T][IN]
    const float* x0      = (const float*)d_in[1];  // [B][HID]
    const float* noise   = (const float*)d_in[2];  // [T][B][HID]
    const float* w_hh    = (const float*)d_in[3];  // [HID][HID]
    const float* W       = (const float*)d_in[4];  // [HID][HID][HID]
    const float* w_in_w  = (const float*)d_in[5];  // [HID][IN]
    const float* w_in_b  = (const float*)d_in[6];  // [HID]
    const float* w_out_w = (const float*)d_in[7];  // [OUT][HID]
    const float* w_out_b = (const float*)d_in[8];  // [OUT]

    float* out    = (float*)d_out;                     // [B][T][OUT]
    float* xfinal = out + (size_t)BSZ * TLEN * OUTW;   // +524288
    float* traj   = xfinal + (size_t)BSZ * HID;        // +16384

    // workspace: x | r0 | r1 | rT0 | rT1  (5 * 16384 floats = 320 KB)
    float* ws = (float*)d_ws;
    float* x      = ws;
    float* rb[2]  = { ws + 16384, ws + 32768 };
    float* rTb[2] = { ws + 49152, ws + 65536 };

    init_kernel<<<64, 256, 0, stream>>>(x0, x, rb[0], rTb[0]);

    for (int t = 0; t < TLEN; ++t) {
        step_kernel<<<256, 256, 0, stream>>>(
            W, w_hh, u, w_in_w, w_in_b,
            noise + (size_t)t * BSZ * HID,
            rb[t & 1], rTb[t & 1],
            x,
            rb[(t + 1) & 1], rTb[(t + 1) & 1],
            traj, t);
    }

    xfinal_kernel<<<64, 256, 0, stream>>>(x, xfinal);
    output_kernel<<<(BSZ * TLEN) / 8, 256, 0, stream>>>(traj, w_out_w, w_out_b, out);
}

// Round 2
// 3116.494 us; speedup vs baseline: 12.8777x; 12.8777x over previous
//
#include <hip/hip_runtime.h>
#include <hip/hip_bf16.h>
#include <math.h>

#define HID 256
#define BSZ 64
#define TLEN 256
#define INW 64
#define OUTW 32
#define NOISE_STD 0.05f
#define TAU 0.2f

typedef __attribute__((ext_vector_type(8))) short short8;
typedef __attribute__((ext_vector_type(4))) float floatx4;

// ---------------------------------------------------------------------------
// one-time: convert W [j][i][k] fp32 -> bf16, swizzled into MFMA B-fragment
// order. B[k][n=i] fragment for (j, kk, ni): lane l holds 8 elems
//   W[j][ i = ni*16 + (l&15) ][ k = kk*32 + (l>>4)*8 + e ],  e=0..7
// flat: Wsw[ ((((j*8+kk)*16+ni)*64+l)*8 + e ]
// ---------------------------------------------------------------------------
__global__ __launch_bounds__(256) void swizzle_kernel(const float* __restrict__ W,
                                                      __hip_bfloat16* __restrict__ Wsw) {
    int g = blockIdx.x * 256 + threadIdx.x;      // 0 .. 2^21-1
    int l  = g & 63;
    int ni = (g >> 6) & 15;
    int kk = (g >> 10) & 7;
    int j  = g >> 13;
    int i  = ni * 16 + (l & 15);
    int k0 = kk * 32 + (l >> 4) * 8;
    const float* __restrict__ src = W + ((size_t)j * HID + i) * HID + k0;
    __hip_bfloat16* __restrict__ dst = Wsw + (size_t)g * 8;
#pragma unroll
    for (int e = 0; e < 8; ++e) dst[e] = __float2bfloat16(src[e]);
}

// ---------------------------------------------------------------------------
// init: x = x0, rbf = bf16(tanh(x0))
// ---------------------------------------------------------------------------
__global__ __launch_bounds__(256) void init_kernel(const float* __restrict__ x0,
                                                   float* __restrict__ x,
                                                   __hip_bfloat16* __restrict__ rbf) {
    int idx = blockIdx.x * 256 + threadIdx.x;    // 0..16383
    float v = x0[idx];
    x[idx] = v;
    rbf[idx] = __float2bfloat16(tanhf(v));
}

// ---------------------------------------------------------------------------
// one recurrent step. block = j (256 blocks), 256 threads = 4 waves.
// GEMM: P[b,i] = sum_k r[b,k] * W[j,i,k]   (M=b=64, N=i=256, K=256, bf16 MFMA)
// epilogue: rec[b] = sum_i r[b,i]*(P[b,i] + w_hh[j,i]) + input_I[b,j]
//           x' = x + NOISE*n + TAU*(rec - x);  traj, r_out
// ---------------------------------------------------------------------------
__global__ __launch_bounds__(256, 1) void step_kernel(
    const __hip_bfloat16* __restrict__ Wsw,   // swizzled [j][kk][ni][lane][8]
    const float* __restrict__ w_hh,           // [HID][HID]
    const float* __restrict__ u,              // [B][T][IN]
    const float* __restrict__ w_in_w,         // [HID][IN]
    const float* __restrict__ w_in_b,         // [HID]
    const float* __restrict__ noise_t,        // [B][HID] slice for this t
    const __hip_bfloat16* __restrict__ r_in,  // [B][HID] bf16
    float* __restrict__ x,                    // [B][HID] fp32 (block j owns col j)
    __hip_bfloat16* __restrict__ r_out,       // [B][HID] bf16
    float* __restrict__ traj,                 // [B][T][HID]
    int t) {
    __shared__ float redw[4][64];

    const int tid  = threadIdx.x;
    const int j    = blockIdx.x;
    const int w    = tid >> 6;
    const int lane = tid & 63;
    const int quad = lane >> 4;
    const int col  = lane & 15;

    floatx4 acc[4][4];   // [mb][nj]
#pragma unroll
    for (int mb = 0; mb < 4; ++mb)
#pragma unroll
        for (int nj = 0; nj < 4; ++nj) acc[mb][nj] = (floatx4){0.f, 0.f, 0.f, 0.f};

    const short* __restrict__ rsh = (const short*)r_in;
    const short* __restrict__ wsh = (const short*)Wsw;

#pragma unroll
    for (int kk = 0; kk < 8; ++kk) {
        short8 afrag[4];
#pragma unroll
        for (int mb = 0; mb < 4; ++mb) {
            int b = mb * 16 + col;
            afrag[mb] = *(const short8*)(rsh + (b * HID + kk * 32 + quad * 8));
        }
#pragma unroll
        for (int nj = 0; nj < 4; ++nj) {
            short8 bfrag = *(const short8*)(wsh +
                ((((size_t)j * 8 + kk) * 16 + (w * 4 + nj)) * 64 + lane) * 8);
#pragma unroll
            for (int mb = 0; mb < 4; ++mb)
                acc[mb][nj] = __builtin_amdgcn_mfma_f32_16x16x32_bf16(
                    afrag[mb], bfrag, acc[mb][nj], 0, 0, 0);
        }
    }

    // epilogue: lane's D elements are (b = mb*16 + quad*4 + reg, i = ni*16 + col)
    float part[16];
#pragma unroll
    for (int p = 0; p < 16; ++p) part[p] = 0.f;

#pragma unroll
    for (int nj = 0; nj < 4; ++nj) {
        int i = (w * 4 + nj) * 16 + col;
        float whh = w_hh[j * HID + i];
#pragma unroll
        for (int mb = 0; mb < 4; ++mb) {
#pragma unroll
            for (int reg = 0; reg < 4; ++reg) {
                int b = mb * 16 + quad * 4 + reg;
                float val = acc[mb][nj][reg] + whh;
                float rv = __bfloat162float(r_in[b * HID + i]);
                part[mb * 4 + reg] = fmaf(rv, val, part[mb * 4 + reg]);
            }
        }
    }

    // reduce across the 16 lanes of each quad (i-columns)
#pragma unroll
    for (int s = 1; s < 16; s <<= 1) {
#pragma unroll
        for (int p = 0; p < 16; ++p) part[p] += __shfl_xor(part[p], s, 64);
    }
    if (col == 0) {
#pragma unroll
        for (int mb = 0; mb < 4; ++mb)
#pragma unroll
            for (int reg = 0; reg < 4; ++reg)
                redw[w][mb * 16 + quad * 4 + reg] = part[mb * 4 + reg];
    }
    __syncthreads();

    if (tid < BSZ) {
        const int b = tid;
        float rec = redw[0][b] + redw[1][b] + redw[2][b] + redw[3][b];

        // input_I[b,j]
        float isum = w_in_b[j];
        const float4* __restrict__ urow =
            (const float4*)(u + ((size_t)b * TLEN + t) * INW);
        const float4* __restrict__ wrow = (const float4*)(w_in_w + (size_t)j * INW);
#pragma unroll
        for (int q = 0; q < INW / 4; ++q) {
            float4 uu = urow[q], ww = wrow[q];
            isum = fmaf(uu.x, ww.x, isum);
            isum = fmaf(uu.y, ww.y, isum);
            isum = fmaf(uu.z, ww.z, isum);
            isum = fmaf(uu.w, ww.w, isum);
        }
        rec += isum;

        const int xi = b * HID + j;
        float xo = x[xi];
        float xn = xo + NOISE_STD * noise_t[xi] + TAU * (rec - xo);
        x[xi] = xn;
        traj[((size_t)b * TLEN + t) * HID + j] = xn;
        r_out[xi] = __float2bfloat16(tanhf(xn));
    }
}

// ---------------------------------------------------------------------------
__global__ __launch_bounds__(256) void xfinal_kernel(const float* __restrict__ x,
                                                     float* __restrict__ xf) {
    int idx = blockIdx.x * 256 + threadIdx.x;
    xf[idx] = x[idx];
}

// ---------------------------------------------------------------------------
// output[b,t,o] = w_out_b[o] + sum_h tanh(traj[b,t,h]) * w_out_w[o,h]
// ---------------------------------------------------------------------------
__global__ __launch_bounds__(256) void output_kernel(
    const float* __restrict__ traj,     // [B][T][HID]
    const float* __restrict__ w_out_w,  // [OUT][HID]
    const float* __restrict__ w_out_b,  // [OUT]
    float* __restrict__ out) {          // [B][T][OUT]
    __shared__ float th[8][HID + 1];
    const int bt0 = blockIdx.x * 8;
    const int tid = threadIdx.x;
#pragma unroll
    for (int m = 0; m < 8; ++m) {
        int idx = m * 256 + tid;
        th[idx >> 8][idx & 255] = tanhf(traj[(size_t)bt0 * HID + idx]);
    }
    __syncthreads();
    const int row = tid >> 5, o = tid & 31;
    const float* __restrict__ wrow = w_out_w + (size_t)o * HID;
    float s = w_out_b[o];
#pragma unroll 8
    for (int h = 0; h < HID; ++h) s = fmaf(th[row][h], wrow[h], s);
    out[(size_t)(bt0 + row) * OUTW + o] = s;
}

// ---------------------------------------------------------------------------
extern "C" void kernel_launch(void* const* d_in, const int* in_sizes, int n_in,
                              void* d_out, int out_size, void* d_ws, size_t ws_size,
                              hipStream_t stream) {
    const float* u       = (const float*)d_in[0];  // [B][T][IN]
    const float* x0      = (const float*)d_in[1];  // [B][HID]
    const float* noise   = (const float*)d_in[2];  // [T][B][HID]
    const float* w_hh    = (const float*)d_in[3];  // [HID][HID]
    const float* W       = (const float*)d_in[4];  // [HID][HID][HID]
    const float* w_in_w  = (const float*)d_in[5];  // [HID][IN]
    const float* w_in_b  = (const float*)d_in[6];  // [HID]
    const float* w_out_w = (const float*)d_in[7];  // [OUT][HID]
    const float* w_out_b = (const float*)d_in[8];  // [OUT]

    float* out    = (float*)d_out;                     // [B][T][OUT]
    float* xfinal = out + (size_t)BSZ * TLEN * OUTW;   // +524288
    float* traj   = xfinal + (size_t)BSZ * HID;        // +16384

    // workspace layout (bytes):
    //   Wsw  : 0              .. 33,554,432   (2^24 bf16)
    //   x    : 33,554,432     .. +65,536      (16384 fp32)
    //   rbf0 : 33,619,968     .. +32,768      (16384 bf16)
    //   rbf1 : 33,652,736     .. +32,768
    char* ws = (char*)d_ws;
    __hip_bfloat16* Wsw = (__hip_bfloat16*)ws;
    float* x = (float*)(ws + 33554432);
    __hip_bfloat16* rbf[2] = { (__hip_bfloat16*)(ws + 33619968),
                               (__hip_bfloat16*)(ws + 33652736) };

    swizzle_kernel<<<8192, 256, 0, stream>>>(W, Wsw);
    init_kernel<<<64, 256, 0, stream>>>(x0, x, rbf[0]);

    for (int t = 0; t < TLEN; ++t) {
        step_kernel<<<256, 256, 0, stream>>>(
            Wsw, w_hh, u, w_in_w, w_in_b,
            noise + (size_t)t * BSZ * HID,
            rbf[t & 1],
            x,
            rbf[(t + 1) & 1],
            traj, t);
    }

    xfinal_kernel<<<64, 256, 0, stream>>>(x, xfinal);
    output_kernel<<<(BSZ * TLEN) / 8, 256, 0, stream>>>(traj, w_out_w, w_out_b, out);
}